// Round 12
// baseline (5342.780 us; speedup 1.0000x reference)
//
#include <hip/hip_runtime.h>

#define N      4096
#define NBLK   256
#define NTHR   1024
#define NT     16           // tile grid: 16 x 16
#define TS     256          // tile side
#define TU     128          // uints per tile row (2 bf16 cols per uint)
#define RPB    16           // rows per block in pair_sum
#define LOG2E  1.4426950408889634f

// Journal (what each round proved):
//  r1-2: never write d_ws (OOB fault => dead container)
//  r0,4: no cooperative launch under graph capture (hang)
//  r5:   __threadfence() = full L2 wb+inv per barrier. NO fences anywhere.
//  r6:   relay barrier + relaxed agent-scope IF$ atomics: correct & cheap.
//  r7/r8/r9: poll cost scales with poller count; single-word coherent
//        hotspots serialize at one IF$ bank; no distributed sync, no flags.
//  r10:  staging coherent reads was never the bottleneck.
//  r11:  5239us: bf16 Gibbs W+WT matvec kills transcendentals (VALU 15%)
//        but W+WT = 8.4MB/XCD thrashes 4MB L2: 9.9GB IF$ @2TB/s = the wall.
//  r12:  2D tiles: ONE W, block (a,b) owns a 256x256 tile used row-wise
//        (f-pass) AND col-wise (g-pass). 33.5MB total = 4.2MB/XCD = L2
//        resident. Cross-tile reduce via 1KB partials + per-block local
//        scale (published), recombined stably by consumers.
struct WS {
  float4 xpack[N];
  float4 ypack[N];
  float  fs[N];      // final potentials (written once at the end)
  float  gs[N];
  double accC;
  double accE;
};
__device__ WS g_ws;

__device__ unsigned g_tile[NBLK][TS * TU];   // 33.5 MB, block-private tiles
__device__ float g_fpart[NT][NT][TS];        // [a][b][i'] row-sum partials
__device__ float g_fA[NT][NT];               // scale used by (a,b) f-sweep
__device__ float g_gpart[NT][NT][TS];        // [b][a][j'] col-sum partials
__device__ float g_gA[NT][NT];

__device__ unsigned g_arrive[NBLK];
__device__ unsigned g_release;
__device__ unsigned g_dead;

#define AL(p)   __hip_atomic_load((p),  __ATOMIC_RELAXED, __HIP_MEMORY_SCOPE_AGENT)
#define AS(p,v) __hip_atomic_store((p),(v), __ATOMIC_RELAXED, __HIP_MEMORY_SCOPE_AGENT)
#define SPIN_MAX 4000000u

__device__ __forceinline__ float  cload (const float*  p){ return __hip_atomic_load(p, __ATOMIC_RELAXED, __HIP_MEMORY_SCOPE_AGENT); }
__device__ __forceinline__ void   cstore(float* p, float v){ __hip_atomic_store(p, v, __ATOMIC_RELAXED, __HIP_MEMORY_SCOPE_AGENT); }
__device__ __forceinline__ double cloadd(const double* p){ return __hip_atomic_load(p, __ATOMIC_RELAXED, __HIP_MEMORY_SCOPE_AGENT); }
__device__ __forceinline__ float  ex2f(float v) { return __builtin_amdgcn_exp2f(v); }
__device__ __forceinline__ float  lg2f(float v) { return __builtin_amdgcn_logf(v); }
__device__ __forceinline__ float  blo(unsigned w) { return __uint_as_float(w << 16); }
__device__ __forceinline__ float  bhi(unsigned w) { return __uint_as_float(w & 0xffff0000u); }

// r6 relay barrier (proven ~1.3-2us, ~511 pollers)
__device__ __forceinline__ void gbar(unsigned k) {
  __syncthreads();
  if (threadIdx.x == 0) AS(&g_arrive[blockIdx.x], k);
  if (blockIdx.x == 0) {
    if (threadIdx.x < NBLK) {
      unsigned t = 0;
      while (AL(&g_arrive[threadIdx.x]) < k) {
        if (AL(&g_dead)) break;
        if (++t > SPIN_MAX) { AS(&g_dead, 1u); break; }
        __builtin_amdgcn_s_sleep(1);
      }
    }
    __syncthreads();
    if (threadIdx.x == 0) AS(&g_release, k);
  } else if (threadIdx.x == 0) {
    unsigned t = 0;
    while (AL(&g_release) < k) {
      if (AL(&g_dead)) break;
      if (++t > SPIN_MAX) { AS(&g_dead, 1u); break; }
      __builtin_amdgcn_s_sleep(2);
    }
  }
  __syncthreads();
}

// ---------------------------------------------------------------------------
// Reduce 16 scaled partials into a potential chunk (all in LDS on exit):
//   pot[t] = 12 - m - log2( Sum_c part[c][t] * 2^(-A_c - m) ),  m = max(-A_c)
// (derivation: V_i = Sum_c P_c * 2^(-A_c-24); pot = -12 - log2 V.)
__device__ void reduce_pot(const float* __restrict__ partBase,   // [16][TS]
                           const float* __restrict__ sclBase,    // [16]
                           float* pot, float* scr, float* scl)
{
  const int tid = threadIdx.x;
  if (tid < NT) scl[tid] = cload(&sclBase[tid]);   // few coherent loads, LDS-cached
  __syncthreads();
  float m = -1e30f;
#pragma unroll
  for (int c = 0; c < NT; ++c) m = fmaxf(m, -scl[c]);
  const int jp  = tid & (TS - 1);
  const int grp = tid >> 8;          // 0..3, covers c = 4*grp .. 4*grp+3
  float s = 0.f;
#pragma unroll
  for (int k = 0; k < 4; ++k) {
    int c = grp * 4 + k;
    s = fmaf(cload(&partBase[c * TS + jp]), ex2f(-scl[c] - m), s);
  }
  scr[grp * TS + jp] = s;
  __syncthreads();
  if (tid < TS) {
    float S = (scr[tid] + scr[TS + tid]) + (scr[2 * TS + tid] + scr[3 * TS + tid]);
    pot[tid] = 12.0f - m - lg2f(S);
  }
  __syncthreads();
}

// chunk max of pot[0..255] -> A = 72 - max; uv[t] = 2^(pot[t] + A); returns A
__device__ float build_uv(const float* pot, float* uv, float* mx4)
{
  const int tid = threadIdx.x, lane = tid & 63, wid = tid >> 6;
  float mv = (tid < TS) ? pot[tid] : -1e30f;
  if (wid < 4) {
#pragma unroll
    for (int off = 32; off; off >>= 1) mv = fmaxf(mv, __shfl_xor(mv, off));
    if (lane == 0) mx4[wid] = mv;
  }
  __syncthreads();
  float A = 72.0f - fmaxf(fmaxf(mx4[0], mx4[1]), fmaxf(mx4[2], mx4[3]));
  if (tid < TS) uv[tid] = ex2f(pot[tid] + A);
  __syncthreads();
  return A;
}

// ---------------------------------------------------------------------------
// pair_sum: exact fp32 C path (r6). emd==0: accC += sum C. emd==1: EMD.
__device__ void pair_sum(int rowBase, int emd, float nie2, double* ldsd)
{
  const int tid  = threadIdx.x;
  const int lane = tid & 63;
  const int wid  = tid >> 6;
  const int rg   = wid >> 2;
  const int ck   = wid & 3;
  const int r0   = rowBase + rg * 4;
  const int j0   = ck * 1024 + lane;

  float pj[16];
#pragma unroll
  for (int t = 0; t < 16; ++t) pj[t] = emd ? cload(&g_ws.gs[j0 + t * 64]) : 0.f;

  float c0[4], c1v[4], c2v[4], ca[4], fr[4];
  double acc[4];
#pragma unroll
  for (int r = 0; r < 4; ++r) {
    float4 p = g_ws.xpack[r0 + r];
    c0[r] = -2.f * p.x; c1v[r] = -2.f * p.y; c2v[r] = -2.f * p.z; ca[r] = p.w;
    fr[r] = emd ? cload(&g_ws.fs[r0 + r]) : 0.f;
    acc[r] = 0.0;
  }
#pragma unroll
  for (int t = 0; t < 16; ++t) {
    float4 q = g_ws.ypack[j0 + t * 64];
    float  b = q.w;
#pragma unroll
    for (int r = 0; r < 4; ++r) {
      float d2 = fmaf(c0[r], q.x, fmaf(c1v[r], q.y, fmaf(c2v[r], q.z, ca[r] + b)));
      float c = __builtin_amdgcn_sqrtf(fmaxf(d2, 1e-12f));
      float term = emd ? ex2f(fmaf(nie2, c, fr[r] + pj[t])) * c : c;
      acc[r] += (double)term;
    }
  }
  double a = (acc[0] + acc[1]) + (acc[2] + acc[3]);
#pragma unroll
  for (int off = 32; off; off >>= 1) a += __shfl_xor(a, off);
  if (lane == 0) ldsd[wid] = a;
  __syncthreads();
  if (tid == 0) {
    double s = 0.0;
#pragma unroll
    for (int w = 0; w < 16; ++w) s += ldsd[w];
    atomicAdd(emd ? &g_ws.accE : &g_ws.accC, s);
  }
  __syncthreads();
}

// ---------------------------------------------------------------------------
__global__ void k_init()
{
  int idx = blockIdx.x * blockDim.x + threadIdx.x;
  if (idx < NBLK) g_arrive[idx] = 0u;
  if (idx == 0) { g_release = 0u; g_dead = 0u; g_ws.accC = 0.0; g_ws.accE = 0.0; }
}

// ---------------------------------------------------------------------------
extern "C" __global__ void __launch_bounds__(NTHR)
emd_all(const float* __restrict__ x, const float* __restrict__ y,
        float* __restrict__ out)
{
  __shared__ float  scr[NT * TS];   // 16 KB: psum / rsum / col-partials
  __shared__ float  pot[TS];
  __shared__ float  uv[TS];
  __shared__ float  scl[NT];
  __shared__ float  mx4[4];
  __shared__ double ldsd[16];

  const int tid = threadIdx.x;
  const int bid = blockIdx.x;
  const int lane = tid & 63, wid = tid >> 6;
  const int a = bid >> 4, b = bid & 15;   // tile coords
  unsigned bk = 1;

  // packs: every block writes the full arrays (benign identical race, r6)
  for (int i = tid; i < N; i += NTHR) {
    float a0 = x[i * 3 + 0], a1 = x[i * 3 + 1], a2 = x[i * 3 + 2];
    g_ws.xpack[i] = make_float4(a0, a1, a2, fmaf(a0, a0, fmaf(a1, a1, a2 * a2)));
    float b0 = y[i * 3 + 0], b1 = y[i * 3 + 1], b2 = y[i * 3 + 2];
    g_ws.ypack[i] = make_float4(b0, b1, b2, fmaf(b0, b0, fmaf(b1, b1, b2 * b2)));
  }
  __syncthreads();

  // eps = 0.02 * mean(C)
  pair_sum(bid * RPB, 0, 0.f, ldsd);
  gbar(bk++);
  const float nie2 = -LOG2E /
      (float)(0.02 * cloadd(&g_ws.accC) / ((double)N * (double)N));

  // build this block's 256x256 bf16 tile: W = bf16(2^(nie2*C + 24))
  unsigned* T = g_tile[bid];
  for (int idx = tid; idx < TS * TU; idx += NTHR) {
    int i = idx >> 7, p = idx & 127;
    float4 xp = g_ws.xpack[a * TS + i];
    float c0 = -2.f * xp.x, c1 = -2.f * xp.y, c2 = -2.f * xp.z, ca = xp.w;
    float4 qa = g_ws.ypack[b * TS + 2 * p];
    float4 qb = g_ws.ypack[b * TS + 2 * p + 1];
    float da = fmaf(c0, qa.x, fmaf(c1, qa.y, fmaf(c2, qa.z, ca + qa.w)));
    float db = fmaf(c0, qb.x, fmaf(c1, qb.y, fmaf(c2, qb.z, ca + qb.w)));
    float wa = ex2f(fmaf(nie2, __builtin_amdgcn_sqrtf(fmaxf(da, 1e-12f)), 24.0f));
    float wb = ex2f(fmaf(nie2, __builtin_amdgcn_sqrtf(fmaxf(db, 1e-12f)), 24.0f));
    unsigned ua = (__float_as_uint(wa) + 0x8000u) >> 16;
    unsigned ub = (__float_as_uint(wb) + 0x8000u) >> 16;
    T[idx] = ua | (ub << 16);
  }
  __syncthreads();   // tile is block-private; same-XCD L2 serves re-reads

  // 300 exact Gauss-Seidel iterations, 2 phases (2 barriers) each
  for (int it = 0; it < 300; ++it) {
    // ---- f-phase: pot = gs chunk for cols Cb; row sums over tile ----
    if (it == 0) {
      if (tid < TS) pot[tid] = -12.0f;   // initial gs
      __syncthreads();
    } else {
      reduce_pot(&g_gpart[b][0][0], &g_gA[b][0], pot, scr, scl);
    }
    float A = build_uv(pot, uv, mx4);
    {
      float u0 = uv[2 * lane], u1 = uv[2 * lane + 1];
      float u2 = uv[128 + 2 * lane], u3 = uv[129 + 2 * lane];
#pragma unroll 4
      for (int r = 0; r < 16; ++r) {
        int i = wid * 16 + r;
        unsigned wA = T[i * TU + lane], wB = T[i * TU + 64 + lane];
        float rs = fmaf(blo(wA), u0, fmaf(bhi(wA), u1,
                   fmaf(blo(wB), u2, bhi(wB) * u3)));
#pragma unroll
        for (int off = 32; off; off >>= 1) rs += __shfl_xor(rs, off);
        if (lane == 0) scr[i] = rs;
      }
    }
    __syncthreads();
    if (tid < TS) cstore(&g_fpart[a][b][tid], scr[tid]);
    if (tid == 0) cstore(&g_fA[a][b], A);
    gbar(bk++);

    // ---- g-phase: pot = fs chunk for rows Ra (fresh, GS); col sums ----
    reduce_pot(&g_fpart[a][0][0], &g_fA[a][0], pot, scr, scl);
    if (it == 299 && b == 0 && tid < TS)      // materialize final fs
      cstore(&g_ws.fs[a * TS + tid], pot[tid]);
    float Av = build_uv(pot, uv, mx4);
    {
      float ca0 = 0.f, ca1 = 0.f, ca2 = 0.f, ca3 = 0.f;
#pragma unroll 4
      for (int r = 0; r < 16; ++r) {
        int i = wid * 16 + r;
        float vv = uv[i];
        unsigned wA = T[i * TU + lane], wB = T[i * TU + 64 + lane];
        ca0 = fmaf(blo(wA), vv, ca0); ca1 = fmaf(bhi(wA), vv, ca1);
        ca2 = fmaf(blo(wB), vv, ca2); ca3 = fmaf(bhi(wB), vv, ca3);
      }
      scr[wid * TS + 2 * lane]       = ca0;
      scr[wid * TS + 2 * lane + 1]   = ca1;
      scr[wid * TS + 128 + 2 * lane] = ca2;
      scr[wid * TS + 129 + 2 * lane] = ca3;
    }
    __syncthreads();
    if (tid < TS) {
      float S = 0.f;
#pragma unroll
      for (int w = 0; w < NT; ++w) S += scr[w * TS + tid];
      cstore(&g_gpart[b][a][tid], S);
    }
    if (tid == 0) cstore(&g_gA[b][a], Av);
    gbar(bk++);
  }

  // materialize final gs
  reduce_pot(&g_gpart[b][0][0], &g_gA[b][0], pot, scr, scl);
  if (a == 0 && tid < TS) cstore(&g_ws.gs[b * TS + tid], pot[tid]);
  gbar(bk++);

  // EMD with exact fp32 C and final potentials
  pair_sum(bid * RPB, 1, nie2, ldsd);
  gbar(bk++);
  if (bid == 0 && tid == 0) out[0] = (float)cloadd(&g_ws.accE);
}

extern "C" void kernel_launch(void* const* d_in, const int* in_sizes, int n_in,
                              void* d_out, int out_size, void* d_ws, size_t ws_size,
                              hipStream_t stream) {
  const float* x = (const float*)d_in[0];
  const float* y = (const float*)d_in[1];
  float* out = (float*)d_out;
  (void)d_ws; (void)ws_size;

  k_init<<<dim3(64), dim3(256), 0, stream>>>();
  emd_all<<<dim3(NBLK), dim3(NTHR), 0, stream>>>(x, y, out);
}